// Round 10
// baseline (101.999 us; speedup 1.0000x reference)
//
#include <hip/hip_runtime.h>

#define D 128

typedef __attribute__((ext_vector_type(8))) short bf16x8;
typedef __attribute__((ext_vector_type(4))) float f32x4;

__device__ __forceinline__ unsigned short f2bf(float f) {
    unsigned int u = __float_as_uint(f);
    unsigned int r = (u + 0x7fffu + ((u >> 16) & 1u)) >> 16;
    return (unsigned short)r;
}
__device__ __forceinline__ float bf_lo(unsigned int u) { return __uint_as_float(u << 16); }
__device__ __forceinline__ float bf_hi(unsigned int u) { return __uint_as_float(u & 0xffff0000u); }

// ---------------- init: zero cnt + segment-base counter ----------------

__global__ void k_init(int* cnt, int* base, int n) {
    int i = blockIdx.x * blockDim.x + threadIdx.x;
    int n4 = n >> 2;
    if (i < n4) ((int4*)cnt)[i] = make_int4(0, 0, 0, 0);
    int rem = n & 3;
    if (rem && i < rem) cnt[n4 * 4 + i] = 0;
    if (i == 0) *base = 0;
}

// count degrees AND record each edge's arrival slot (runs ALONE: co-residency
// with the gemm regressed 2x in R8/R9 -- atomic+streaming L2 interference)
__global__ void k_count_v4(const int* dst, int* cnt, int* slot, int e4) {
    int i = blockIdx.x * blockDim.x + threadIdx.x;
    if (i < e4) {
        int4 d = ((const int4*)dst)[i];
        int s0 = atomicAdd(&cnt[d.x], 1);
        int s1 = atomicAdd(&cnt[d.y], 1);
        int s2 = atomicAdd(&cnt[d.z], 1);
        int s3 = atomicAdd(&cnt[d.w], 1);
        ((int4*)slot)[i] = make_int4(s0, s1, s2, s3);
    }
}

__global__ void k_count_s(const int* dst, int* cnt, int* slot, int e) {
    int i = blockIdx.x * blockDim.x + threadIdx.x;
    if (i < e) slot[i] = atomicAdd(&cnt[dst[i]], 1);
}

// ---------------- scan: off[i] = GLOBAL exclusive offset (atomic block base) ----
// Segment order across blocks is irrelevant (gather only needs contiguity),
// so one atomicAdd per block replaces the second-level scan + bscan indirection.

__global__ __launch_bounds__(512) void k_scan(const int* __restrict__ cnt,
                                              int* __restrict__ off,
                                              float* __restrict__ dinv,
                                              int* __restrict__ base, int n) {
    __shared__ int s[512];
    __shared__ int bbase;
    int t = threadIdx.x;
    int i = blockIdx.x * 512 + t;
    int v = (i < n) ? cnt[i] : 0;
    if (i < n) dinv[i] = rsqrtf((float)(v + 1));
    s[t] = v;
    __syncthreads();
    for (int d2 = 1; d2 < 512; d2 <<= 1) {
        int add = (t >= d2) ? s[t - d2] : 0;
        __syncthreads();
        s[t] += add;
        __syncthreads();
    }
    if (t == 511) bbase = atomicAdd(base, s[511]);
    __syncthreads();
    if (i < n) off[i] = bbase + s[t] - v;
}

// ---------------- fused: h_scaled = dinv*(x@W) (blocks [0,gb)) + permute (rest) --
// R7-proven pairing: HBM-bound gemm + fire-and-forget scattered stores.

__global__ __launch_bounds__(512) void k_gemm_perm(const float* __restrict__ x,
                                                   const float* __restrict__ W,
                                                   const float* __restrict__ dinv,
                                                   unsigned short* __restrict__ h, int n,
                                                   int gb,
                                                   const int* __restrict__ src,
                                                   const int* __restrict__ dst,
                                                   const int* __restrict__ off,
                                                   const int* __restrict__ slot,
                                                   int* __restrict__ ssrc, int e4) {
    __shared__ __align__(16) unsigned short Wt[D * D];  // [col][k^swz], 32 KB
    int t = threadIdx.x;

    if ((int)blockIdx.x >= gb) {
        // -------- permute branch (int4, atomic-free) --------
        int i = ((int)blockIdx.x - gb) * 512 + t;
        if (i < e4) {
            int4 sv = ((const int4*)src)[i];
            int4 d  = ((const int4*)dst)[i];
            int4 sl = ((const int4*)slot)[i];
            ssrc[off[d.x] + sl.x] = sv.x;
            ssrc[off[d.y] + sl.y] = sv.y;
            ssrc[off[d.z] + sl.z] = sv.z;
            ssrc[off[d.w] + sl.w] = sv.w;
        }
        return;
    }

    // -------- gemm branch: h = bf16(dinv * (x @ W)) --------
#pragma unroll
    for (int i2 = 0; i2 < 32; ++i2) {
        int e = t + i2 * 512;
        int k = e >> 7, nn = e & 127;
        Wt[nn * D + (k ^ ((nn & 7) << 3))] = f2bf(W[e]);
    }
    __syncthreads();

    int wave = t >> 6, lane = t & 63;
    int lr = lane & 15;
    int lk = (lane >> 4) << 3;
    int row = blockIdx.x * 128 + wave * 16 + lr;
    int rclamp = row < n ? row : n - 1;

    bf16x8 afrag[4];
    const float* xr = x + (size_t)rclamp * D;
#pragma unroll
    for (int kt = 0; kt < 4; ++kt) {
        int k0 = kt * 32 + lk;
        float4 lo = *(const float4*)(xr + k0);
        float4 hi = *(const float4*)(xr + k0 + 4);
        bf16x8 a;
        a[0] = f2bf(lo.x); a[1] = f2bf(lo.y); a[2] = f2bf(lo.z); a[3] = f2bf(lo.w);
        a[4] = f2bf(hi.x); a[5] = f2bf(hi.y); a[6] = f2bf(hi.z); a[7] = f2bf(hi.w);
        afrag[kt] = a;
    }

    int orow0 = blockIdx.x * 128 + wave * 16 + ((lane >> 4) << 2);
    float dv[4];
#pragma unroll
    for (int r = 0; r < 4; ++r) {
        int orow = orow0 + r;
        dv[r] = dinv[orow < n ? orow : n - 1];
    }

#pragma unroll
    for (int c = 0; c < 8; ++c) {
        f32x4 acc = {0.f, 0.f, 0.f, 0.f};
        int col = c * 16 + lr;
#pragma unroll
        for (int kt = 0; kt < 4; ++kt) {
            int k0 = kt * 32 + lk;
            bf16x8 bfr = *(const bf16x8*)&Wt[col * D + (k0 ^ ((col & 7) << 3))];
            acc = __builtin_amdgcn_mfma_f32_16x16x32_bf16(afrag[kt], bfr, acc, 0, 0, 0);
        }
#pragma unroll
        for (int r = 0; r < 4; ++r) {
            int orow = orow0 + r;
            if (orow < n) h[(size_t)orow * D + col] = f2bf(acc[r] * dv[r]);
        }
    }
}

// scalar permute fallback
__global__ void k_permute_s(const int* src, const int* dst, const int* off,
                            const int* slot, int* ssrc, int e) {
    int i = blockIdx.x * blockDim.x + threadIdx.x;
    if (i < e) {
        int d = dst[i];
        ssrc[off[d] + slot[i]] = src[i];
    }
}

// ---------------- gather: out = relu(dinv[dst] * sum(h_scaled) + b) --------------
// 16 lanes per node, uint4 (8 bf16) per lane.

__global__ __launch_bounds__(256) void k_gather4(const unsigned short* __restrict__ h,
                                                 const float* __restrict__ dinv,
                                                 const int* __restrict__ off,
                                                 const int* __restrict__ cnt,
                                                 const int* __restrict__ ssrc,
                                                 const float* __restrict__ b,
                                                 float* __restrict__ out, int n) {
    int gid = blockIdx.x * 256 + threadIdx.x;
    int node = gid >> 4;           // 16 lanes per node
    int li = gid & 15;             // covers cols li*8 .. li*8+7
    if (node >= n) return;
    float di = dinv[node];
    const uint4* h4 = (const uint4*)h;      // one row = 16 uint4
    uint4 u = h4[(size_t)node * 16 + li];   // self term (h already dinv-scaled)
    float acc[8];
    acc[0] = bf_lo(u.x); acc[1] = bf_hi(u.x);
    acc[2] = bf_lo(u.y); acc[3] = bf_hi(u.y);
    acc[4] = bf_lo(u.z); acc[5] = bf_hi(u.z);
    acc[6] = bf_lo(u.w); acc[7] = bf_hi(u.w);

    int m = cnt[node];
    int s0 = off[node];

    for (int j = 0; j < m; j += 8) {
        uint4 v[8];
        float w[8];
#pragma unroll
        for (int k = 0; k < 8; ++k) {
            int jk = j + k;
            int idx = jk < m ? jk : m - 1;
            int s = ssrc[s0 + idx];
            v[k] = h4[(size_t)s * 16 + li];
            w[k] = jk < m ? 1.f : 0.f;
        }
#pragma unroll
        for (int k = 0; k < 8; ++k) {
            acc[0] = fmaf(w[k], bf_lo(v[k].x), acc[0]);
            acc[1] = fmaf(w[k], bf_hi(v[k].x), acc[1]);
            acc[2] = fmaf(w[k], bf_lo(v[k].y), acc[2]);
            acc[3] = fmaf(w[k], bf_hi(v[k].y), acc[3]);
            acc[4] = fmaf(w[k], bf_lo(v[k].z), acc[4]);
            acc[5] = fmaf(w[k], bf_hi(v[k].z), acc[5]);
            acc[6] = fmaf(w[k], bf_lo(v[k].w), acc[6]);
            acc[7] = fmaf(w[k], bf_hi(v[k].w), acc[7]);
        }
    }

    const float4* b4 = (const float4*)b;
    float4 bb0 = b4[li * 2], bb1 = b4[li * 2 + 1];
    float4 o0, o1;
    o0.x = fmaxf(fmaf(di, acc[0], bb0.x), 0.f);
    o0.y = fmaxf(fmaf(di, acc[1], bb0.y), 0.f);
    o0.z = fmaxf(fmaf(di, acc[2], bb0.z), 0.f);
    o0.w = fmaxf(fmaf(di, acc[3], bb0.w), 0.f);
    o1.x = fmaxf(fmaf(di, acc[4], bb1.x), 0.f);
    o1.y = fmaxf(fmaf(di, acc[5], bb1.y), 0.f);
    o1.z = fmaxf(fmaf(di, acc[6], bb1.z), 0.f);
    o1.w = fmaxf(fmaf(di, acc[7], bb1.w), 0.f);
    float4* o4 = (float4*)out;              // one row = 32 float4
    o4[(size_t)node * 32 + li * 2] = o0;
    o4[(size_t)node * 32 + li * 2 + 1] = o1;
}

// ---------------- fp32 fallback (small ws): atomic scatter ----------------

__global__ void k_count_plain(const int* dst, int* cnt, int e) {
    int i = blockIdx.x * blockDim.x + threadIdx.x;
    if (i < e) atomicAdd(&cnt[dst[i]], 1);
}

__global__ void k_dinv_only(const int* cnt, float* dinv, int n) {
    int i = blockIdx.x * blockDim.x + threadIdx.x;
    if (i < n) dinv[i] = rsqrtf((float)(cnt[i] + 1));
}

__global__ void k_self(const float* x, const float* dinv, float* out, int n) {
    int gid = blockIdx.x * blockDim.x + threadIdx.x;
    if (gid < n * 32) {
        int row = gid >> 5;
        float di = dinv[row];
        float w0 = di * di;
        float4 v = ((const float4*)x)[gid];
        v.x *= w0; v.y *= w0; v.z *= w0; v.w *= w0;
        ((float4*)out)[gid] = v;
    }
}

__global__ void k_scatter_atomic(const float* x, const int* src, const int* dst,
                                 const float* dinv, float* out, int e) {
    int gid = blockIdx.x * blockDim.x + threadIdx.x;
    int eid = gid >> 5, q = gid & 31;
    if (eid >= e) return;
    int s = src[eid], d = dst[eid];
    float c = dinv[s] * dinv[d];
    float4 v = ((const float4*)x)[(size_t)s * 32 + q];
    float* o = out + (size_t)d * D + q * 4;
    atomicAdd(o + 0, c * v.x);
    atomicAdd(o + 1, c * v.y);
    atomicAdd(o + 2, c * v.z);
    atomicAdd(o + 3, c * v.w);
}

__global__ __launch_bounds__(512) void k_gemm_relu(float* io, const float* W,
                                                   const float* b, int n) {
    __shared__ float4 Wl[D * 32];
    int t = threadIdx.x;
    const float4* W4 = (const float4*)W;
#pragma unroll
    for (int q = 0; q < 8; ++q) Wl[t + q * 512] = W4[t + q * 512];
    __syncthreads();
    int tx = t & 31, ty = t >> 5;
    int row0 = blockIdx.x * 128;
    const float4* a4 = (const float4*)io;
    int rb[8];
#pragma unroll
    for (int r = 0; r < 8; ++r) {
        int gr = row0 + ty * 8 + r;
        if (gr > n - 1) gr = n - 1;
        rb[r] = gr * 32;
    }
    float4 bb = ((const float4*)b)[tx];
    float4 acc[8];
#pragma unroll
    for (int r = 0; r < 8; ++r) acc[r] = bb;
    for (int k4 = 0; k4 < 32; ++k4) {
        float4 a[8];
#pragma unroll
        for (int r = 0; r < 8; ++r) a[r] = a4[(size_t)rb[r] + k4];
#pragma unroll
        for (int kk = 0; kk < 4; ++kk) {
            float4 w = Wl[(k4 * 4 + kk) * 32 + tx];
#pragma unroll
            for (int r = 0; r < 8; ++r) {
                float av = (kk == 0) ? a[r].x : (kk == 1) ? a[r].y
                           : (kk == 2) ? a[r].z : a[r].w;
                acc[r].x += av * w.x;
                acc[r].y += av * w.y;
                acc[r].z += av * w.z;
                acc[r].w += av * w.w;
            }
        }
    }
    __syncthreads();
    float4* o4 = (float4*)io;
#pragma unroll
    for (int r = 0; r < 8; ++r) {
        int gr = row0 + ty * 8 + r;
        if (gr < n) {
            float4 v = acc[r];
            v.x = fmaxf(v.x, 0.f); v.y = fmaxf(v.y, 0.f);
            v.z = fmaxf(v.z, 0.f); v.w = fmaxf(v.w, 0.f);
            o4[(size_t)gr * 32 + tx] = v;
        }
    }
}

// ---------------- launch ----------------

extern "C" void kernel_launch(void* const* d_in, const int* in_sizes, int n_in,
                              void* d_out, int out_size, void* d_ws, size_t ws_size,
                              hipStream_t stream) {
    const float* x = (const float*)d_in[0];
    const int* ei = (const int*)d_in[1];
    const float* W = (const float*)d_in[2];
    const float* b = (const float*)d_in[3];
    float* out = (float*)d_out;

    int n = in_sizes[0] / D;
    int e = in_sizes[1] / 2;
    const int* src = ei;
    const int* dst = ei + e;

    char* ws = (char*)d_ws;
    size_t nB = (size_t)n * 4;
    size_t o_cnt = 0;
    size_t o_off = nB;
    size_t o_dinv = 2 * nB;
    size_t o_base = 3 * nB;                       // 1 int (16B reserved)
    size_t o_slot = 3 * nB + 16;
    size_t o_ssrc = (o_slot + (size_t)e * 4 + 15) & ~(size_t)15;
    size_t o_h = (o_ssrc + (size_t)e * 4 + 15) & ~(size_t)15;
    size_t need = o_h + (size_t)n * D * 2;

    int* cnt    = (int*)(ws + o_cnt);
    int* off    = (int*)(ws + o_off);
    float* dinv = (float*)(ws + o_dinv);
    int* base   = (int*)(ws + o_base);
    int* slot   = (int*)(ws + o_slot);
    int* ssrc   = (int*)(ws + o_ssrc);
    unsigned short* h = (unsigned short*)(ws + o_h);

    int gb = (n + 127) / 128;                     // gemm blocks (128 rows each)
    int sb = (n + 511) / 512;                     // scan blocks (512 nodes each)
    int n4 = (n + 3) / 4;
    // int4 paths need e%4==0 and 16B-aligned src/dst (dst = ei + e)
    bool vec4 = ((e & 3) == 0) && ((((uintptr_t)ei) & 15) == 0) && (((e * 4) & 15) == 0);

    if (ws_size >= need) {
        k_init<<<(n4 + 255) / 256, 256, 0, stream>>>(cnt, base, n);
        if (vec4) {
            int e4 = e >> 2;
            int pb = (e4 + 511) / 512;             // permute blocks
            k_count_v4<<<(e4 + 255) / 256, 256, 0, stream>>>(dst, cnt, slot, e4);
            k_scan<<<sb, 512, 0, stream>>>(cnt, off, dinv, base, n);
            k_gemm_perm<<<gb + pb, 512, 0, stream>>>(x, W, dinv, h, n, gb,
                                                     src, dst, off, slot, ssrc, e4);
        } else {
            int eb = (e + 255) / 256;
            k_count_s<<<eb, 256, 0, stream>>>(dst, cnt, slot, e);
            k_scan<<<sb, 512, 0, stream>>>(cnt, off, dinv, base, n);
            k_permute_s<<<eb, 256, 0, stream>>>(src, dst, off, slot, ssrc, e);
            k_gemm_perm<<<gb, 512, 0, stream>>>(x, W, dinv, h, n, gb,
                                                src, dst, off, slot, ssrc, 0);
        }
        int gblocks = ((size_t)n * 16 + 255) / 256;
        k_gather4<<<gblocks, 256, 0, stream>>>(h, dinv, off, cnt, ssrc, b, out, n);
    } else {
        // fp32 atomic-scatter fallback (needs only ~1.2 MB ws)
        int nb = (n + 255) / 256;
        int eb = (e + 255) / 256;
        float* dinv2 = (float*)(ws + nB);
        k_init<<<(n4 + 255) / 256, 256, 0, stream>>>(cnt, base, n);
        k_count_plain<<<eb, 256, 0, stream>>>(dst, cnt, e);
        k_dinv_only<<<nb, 256, 0, stream>>>(cnt, dinv2, n);
        k_self<<<(n * 32 + 255) / 256, 256, 0, stream>>>(x, dinv2, out, n);
        k_scatter_atomic<<<((size_t)e * 32 + 255) / 256, 256, 0, stream>>>(
            x, src, dst, dinv2, out, e);
        k_gemm_relu<<<(n + 127) / 128, 512, 0, stream>>>(out, W, b, n);
    }
}

// Round 11
// 94.631 us; speedup vs baseline: 1.0779x; 1.0779x over previous
//
#include <hip/hip_runtime.h>

#define D 128
#define NBMAX 512   // max scan blocks (n <= 131072)

typedef __attribute__((ext_vector_type(8))) short bf16x8;
typedef __attribute__((ext_vector_type(4))) float f32x4;

__device__ __forceinline__ unsigned short f2bf(float f) {
    unsigned int u = __float_as_uint(f);
    unsigned int r = (u + 0x7fffu + ((u >> 16) & 1u)) >> 16;
    return (unsigned short)r;
}
__device__ __forceinline__ float bf_lo(unsigned int u) { return __uint_as_float(u << 16); }
__device__ __forceinline__ float bf_hi(unsigned int u) { return __uint_as_float(u & 0xffff0000u); }

// ---------------- preprocessing ----------------

__global__ void k_init(int* cnt, int n) {
    int i = blockIdx.x * blockDim.x + threadIdx.x;
    int n4 = n >> 2;
    if (i < n4) ((int4*)cnt)[i] = make_int4(0, 0, 0, 0);
    int rem = n & 3;
    if (rem && i < rem) cnt[n4 * 4 + i] = 0;
}

// count degrees AND record each edge's arrival slot (removes permute's atomic)
__global__ void k_count_v4(const int* dst, int* cnt, int* slot, int e4) {
    int i = blockIdx.x * blockDim.x + threadIdx.x;
    if (i < e4) {
        int4 d = ((const int4*)dst)[i];
        int s0 = atomicAdd(&cnt[d.x], 1);
        int s1 = atomicAdd(&cnt[d.y], 1);
        int s2 = atomicAdd(&cnt[d.z], 1);
        int s3 = atomicAdd(&cnt[d.w], 1);
        ((int4*)slot)[i] = make_int4(s0, s1, s2, s3);
    }
}

__global__ void k_count_s(const int* dst, int* cnt, int* slot, int e) {
    int i = blockIdx.x * blockDim.x + threadIdx.x;
    if (i < e) slot[i] = atomicAdd(&cnt[dst[i]], 1);
}

// block-local exclusive scan + dinv = rsqrt(deg+1)
__global__ __launch_bounds__(256) void k_scan_block(const int* cnt, int* off, int* bsum,
                                                    float* dinv, int n) {
    __shared__ int s[256];
    int t = threadIdx.x;
    int i = blockIdx.x * 256 + t;
    int v = (i < n) ? cnt[i] : 0;
    if (i < n) dinv[i] = rsqrtf((float)(v + 1));
    s[t] = v;
    __syncthreads();
    for (int d2 = 1; d2 < 256; d2 <<= 1) {
        int add = (t >= d2) ? s[t - d2] : 0;
        __syncthreads();
        s[t] += add;
        __syncthreads();
    }
    if (i < n) off[i] = s[t] - v;          // block-local exclusive
    if (t == 255) bsum[blockIdx.x] = s[255];
}

// one block: exclusive scan of block sums -> bscan
__global__ __launch_bounds__(512) void k_scan_bsum(const int* bsum, int* bscan, int nb) {
    __shared__ int s[NBMAX];
    int t = threadIdx.x;
    int v = (t < nb) ? bsum[t] : 0;
    s[t] = v;
    __syncthreads();
    for (int d2 = 1; d2 < NBMAX; d2 <<= 1) {
        int add = (t >= d2) ? s[t - d2] : 0;
        __syncthreads();
        s[t] += add;
        __syncthreads();
    }
    if (t < nb) bscan[t] = s[t] - v;
}

// scalar permute (fallback when edge array not int4-compatible)
__global__ void k_permute_s(const int* src, const int* dst, const int* off,
                            const int* bscan, const int* slot, int* ssrc, int e) {
    int i = blockIdx.x * blockDim.x + threadIdx.x;
    if (i < e) {
        int d = dst[i];
        ssrc[bscan[d >> 8] + off[d] + slot[i]] = src[i];
    }
}

// ---------------- fused: h_scaled = dinv*(x@W) (blocks [0,gb)) + permute (rest) ----
// gemm and permute are independent; fusing lets permute ride along free while
// the MFMA blocks own the machine (grid = gb + pb ~= 4 blocks/CU exactly).

__global__ __launch_bounds__(512) void k_gemm_perm(const float* __restrict__ x,
                                                   const float* __restrict__ W,
                                                   const float* __restrict__ dinv,
                                                   unsigned short* __restrict__ h, int n,
                                                   int gb,
                                                   const int* __restrict__ src,
                                                   const int* __restrict__ dst,
                                                   const int* __restrict__ off,
                                                   const int* __restrict__ bscan,
                                                   const int* __restrict__ slot,
                                                   int* __restrict__ ssrc, int e4) {
    __shared__ __align__(16) unsigned short Wt[D * D];  // [col][k^swz], 32 KB
    int t = threadIdx.x;

    if ((int)blockIdx.x >= gb) {
        // -------- permute branch (int4) --------
        int i = ((int)blockIdx.x - gb) * 512 + t;
        if (i < e4) {
            int4 sv = ((const int4*)src)[i];
            int4 d  = ((const int4*)dst)[i];
            int4 sl = ((const int4*)slot)[i];
            ssrc[bscan[d.x >> 8] + off[d.x] + sl.x] = sv.x;
            ssrc[bscan[d.y >> 8] + off[d.y] + sl.y] = sv.y;
            ssrc[bscan[d.z >> 8] + off[d.z] + sl.z] = sv.z;
            ssrc[bscan[d.w >> 8] + off[d.w] + sl.w] = sv.w;
        }
        return;
    }

    // -------- gemm branch --------
#pragma unroll
    for (int i = 0; i < 32; ++i) {
        int e = t + i * 512;
        int k = e >> 7, nn = e & 127;
        Wt[nn * D + (k ^ ((nn & 7) << 3))] = f2bf(W[e]);
    }
    __syncthreads();

    int wave = t >> 6, lane = t & 63;
    int lr = lane & 15;
    int lk = (lane >> 4) << 3;
    int row = blockIdx.x * 128 + wave * 16 + lr;
    int rclamp = row < n ? row : n - 1;

    bf16x8 afrag[4];
    const float* xr = x + (size_t)rclamp * D;
#pragma unroll
    for (int kt = 0; kt < 4; ++kt) {
        int k0 = kt * 32 + lk;
        float4 lo = *(const float4*)(xr + k0);
        float4 hi = *(const float4*)(xr + k0 + 4);
        bf16x8 a;
        a[0] = f2bf(lo.x); a[1] = f2bf(lo.y); a[2] = f2bf(lo.z); a[3] = f2bf(lo.w);
        a[4] = f2bf(hi.x); a[5] = f2bf(hi.y); a[6] = f2bf(hi.z); a[7] = f2bf(hi.w);
        afrag[kt] = a;
    }

    int orow0 = blockIdx.x * 128 + wave * 16 + ((lane >> 4) << 2);
    float dv[4];
#pragma unroll
    for (int r = 0; r < 4; ++r) {
        int orow = orow0 + r;
        dv[r] = dinv[orow < n ? orow : n - 1];
    }

#pragma unroll
    for (int c = 0; c < 8; ++c) {
        f32x4 acc = {0.f, 0.f, 0.f, 0.f};
        int col = c * 16 + lr;
#pragma unroll
        for (int kt = 0; kt < 4; ++kt) {
            int k0 = kt * 32 + lk;
            bf16x8 bfr = *(const bf16x8*)&Wt[col * D + (k0 ^ ((col & 7) << 3))];
            acc = __builtin_amdgcn_mfma_f32_16x16x32_bf16(afrag[kt], bfr, acc, 0, 0, 0);
        }
#pragma unroll
        for (int r = 0; r < 4; ++r) {
            int orow = orow0 + r;
            if (orow < n) h[(size_t)orow * D + col] = f2bf(acc[r] * dv[r]);
        }
    }
}

// ---------------- gather: out = relu(dinv[dst] * sum(h_scaled) + b) --------------
// 16 lanes per node, uint4 (8 bf16) per lane: 4x wider VMEM, 4x fewer waves.

__global__ __launch_bounds__(256) void k_gather4(const unsigned short* __restrict__ h,
                                                 const float* __restrict__ dinv,
                                                 const int* __restrict__ off,
                                                 const int* __restrict__ cnt,
                                                 const int* __restrict__ bscan,
                                                 const int* __restrict__ ssrc,
                                                 const float* __restrict__ b,
                                                 float* __restrict__ out, int n) {
    int gid = blockIdx.x * 256 + threadIdx.x;
    int node = gid >> 4;           // 16 lanes per node
    int li = gid & 15;             // covers cols li*8 .. li*8+7
    if (node >= n) return;
    float di = dinv[node];
    const uint4* h4 = (const uint4*)h;      // one row = 16 uint4
    uint4 u = h4[(size_t)node * 16 + li];   // self term (h already dinv-scaled)
    float acc[8];
    acc[0] = bf_lo(u.x); acc[1] = bf_hi(u.x);
    acc[2] = bf_lo(u.y); acc[3] = bf_hi(u.y);
    acc[4] = bf_lo(u.z); acc[5] = bf_hi(u.z);
    acc[6] = bf_lo(u.w); acc[7] = bf_hi(u.w);

    int m = cnt[node];
    int s0 = bscan[node >> 8] + off[node];

    for (int j = 0; j < m; j += 8) {
        uint4 v[8];
        float w[8];
#pragma unroll
        for (int k = 0; k < 8; ++k) {
            int jk = j + k;
            int idx = jk < m ? jk : m - 1;
            int s = ssrc[s0 + idx];
            v[k] = h4[(size_t)s * 16 + li];
            w[k] = jk < m ? 1.f : 0.f;
        }
#pragma unroll
        for (int k = 0; k < 8; ++k) {
            acc[0] = fmaf(w[k], bf_lo(v[k].x), acc[0]);
            acc[1] = fmaf(w[k], bf_hi(v[k].x), acc[1]);
            acc[2] = fmaf(w[k], bf_lo(v[k].y), acc[2]);
            acc[3] = fmaf(w[k], bf_hi(v[k].y), acc[3]);
            acc[4] = fmaf(w[k], bf_lo(v[k].z), acc[4]);
            acc[5] = fmaf(w[k], bf_hi(v[k].z), acc[5]);
            acc[6] = fmaf(w[k], bf_lo(v[k].w), acc[6]);
            acc[7] = fmaf(w[k], bf_hi(v[k].w), acc[7]);
        }
    }

    const float4* b4 = (const float4*)b;
    float4 bb0 = b4[li * 2], bb1 = b4[li * 2 + 1];
    float4 o0, o1;
    o0.x = fmaxf(fmaf(di, acc[0], bb0.x), 0.f);
    o0.y = fmaxf(fmaf(di, acc[1], bb0.y), 0.f);
    o0.z = fmaxf(fmaf(di, acc[2], bb0.z), 0.f);
    o0.w = fmaxf(fmaf(di, acc[3], bb0.w), 0.f);
    o1.x = fmaxf(fmaf(di, acc[4], bb1.x), 0.f);
    o1.y = fmaxf(fmaf(di, acc[5], bb1.y), 0.f);
    o1.z = fmaxf(fmaf(di, acc[6], bb1.z), 0.f);
    o1.w = fmaxf(fmaf(di, acc[7], bb1.w), 0.f);
    float4* o4 = (float4*)out;              // one row = 32 float4
    o4[(size_t)node * 32 + li * 2] = o0;
    o4[(size_t)node * 32 + li * 2 + 1] = o1;
}

// ---------------- fp32 fallback (small ws): atomic scatter ----------------

__global__ void k_count_plain(const int* dst, int* cnt, int e) {
    int i = blockIdx.x * blockDim.x + threadIdx.x;
    if (i < e) atomicAdd(&cnt[dst[i]], 1);
}

__global__ void k_dinv_only(const int* cnt, float* dinv, int n) {
    int i = blockIdx.x * blockDim.x + threadIdx.x;
    if (i < n) dinv[i] = rsqrtf((float)(cnt[i] + 1));
}

__global__ void k_self(const float* x, const float* dinv, float* out, int n) {
    int gid = blockIdx.x * blockDim.x + threadIdx.x;
    if (gid < n * 32) {
        int row = gid >> 5;
        float di = dinv[row];
        float w0 = di * di;
        float4 v = ((const float4*)x)[gid];
        v.x *= w0; v.y *= w0; v.z *= w0; v.w *= w0;
        ((float4*)out)[gid] = v;
    }
}

__global__ void k_scatter_atomic(const float* x, const int* src, const int* dst,
                                 const float* dinv, float* out, int e) {
    int gid = blockIdx.x * blockDim.x + threadIdx.x;
    int eid = gid >> 5, q = gid & 31;
    if (eid >= e) return;
    int s = src[eid], d = dst[eid];
    float c = dinv[s] * dinv[d];
    float4 v = ((const float4*)x)[(size_t)s * 32 + q];
    float* o = out + (size_t)d * D + q * 4;
    atomicAdd(o + 0, c * v.x);
    atomicAdd(o + 1, c * v.y);
    atomicAdd(o + 2, c * v.z);
    atomicAdd(o + 3, c * v.w);
}

__global__ __launch_bounds__(512) void k_gemm_relu(float* io, const float* W,
                                                   const float* b, int n) {
    __shared__ float4 Wl[D * 32];
    int t = threadIdx.x;
    const float4* W4 = (const float4*)W;
#pragma unroll
    for (int q = 0; q < 8; ++q) Wl[t + q * 512] = W4[t + q * 512];
    __syncthreads();
    int tx = t & 31, ty = t >> 5;
    int row0 = blockIdx.x * 128;
    const float4* a4 = (const float4*)io;
    int rb[8];
#pragma unroll
    for (int r = 0; r < 8; ++r) {
        int gr = row0 + ty * 8 + r;
        if (gr > n - 1) gr = n - 1;
        rb[r] = gr * 32;
    }
    float4 bb = ((const float4*)b)[tx];
    float4 acc[8];
#pragma unroll
    for (int r = 0; r < 8; ++r) acc[r] = bb;
    for (int k4 = 0; k4 < 32; ++k4) {
        float4 a[8];
#pragma unroll
        for (int r = 0; r < 8; ++r) a[r] = a4[(size_t)rb[r] + k4];
#pragma unroll
        for (int kk = 0; kk < 4; ++kk) {
            float4 w = Wl[(k4 * 4 + kk) * 32 + tx];
#pragma unroll
            for (int r = 0; r < 8; ++r) {
                float av = (kk == 0) ? a[r].x : (kk == 1) ? a[r].y
                           : (kk == 2) ? a[r].z : a[r].w;
                acc[r].x += av * w.x;
                acc[r].y += av * w.y;
                acc[r].z += av * w.z;
                acc[r].w += av * w.w;
            }
        }
    }
    __syncthreads();
    float4* o4 = (float4*)io;
#pragma unroll
    for (int r = 0; r < 8; ++r) {
        int gr = row0 + ty * 8 + r;
        if (gr < n) {
            float4 v = acc[r];
            v.x = fmaxf(v.x, 0.f); v.y = fmaxf(v.y, 0.f);
            v.z = fmaxf(v.z, 0.f); v.w = fmaxf(v.w, 0.f);
            o4[(size_t)gr * 32 + tx] = v;
        }
    }
}

// ---------------- launch ----------------

extern "C" void kernel_launch(void* const* d_in, const int* in_sizes, int n_in,
                              void* d_out, int out_size, void* d_ws, size_t ws_size,
                              hipStream_t stream) {
    const float* x = (const float*)d_in[0];
    const int* ei = (const int*)d_in[1];
    const float* W = (const float*)d_in[2];
    const float* b = (const float*)d_in[3];
    float* out = (float*)d_out;

    int n = in_sizes[0] / D;
    int e = in_sizes[1] / 2;
    const int* src = ei;
    const int* dst = ei + e;

    char* ws = (char*)d_ws;
    size_t nB = (size_t)n * 4;
    int* cnt    = (int*)(ws);
    int* off    = (int*)(ws + nB);
    float* dinv = (float*)(ws + 2 * nB);
    int* bsum   = (int*)(ws + 3 * nB);                 // NBMAX ints
    int* bscan  = (int*)(ws + 3 * nB + 2048);          // NBMAX ints
    int* slot   = (int*)(ws + 3 * nB + 4096);
    int* ssrc   = (int*)(ws + 3 * nB + 4096 + (size_t)e * 4);
    unsigned short* h = (unsigned short*)(ws + 3 * nB + 4096 + (size_t)e * 8);
    size_t need = 3 * nB + 4096 + (size_t)e * 8 + (size_t)n * D * 2;

    int nb = (n + 255) / 256;
    int eb = (e + 255) / 256;
    int gb = (n + 127) / 128;                          // gemm blocks
    // int4 paths need e%4==0 and 16B-aligned src/dst (dst = ei + e)
    bool vec4 = ((e & 3) == 0) && ((((uintptr_t)ei) & 15) == 0) && (((e * 4) & 15) == 0);

    if (ws_size >= need && nb <= NBMAX) {
        k_init<<<(n / 4 + 256) / 256, 256, 0, stream>>>(cnt, n);
        if (vec4) {
            int e4 = e >> 2;
            int pb = (e4 + 511) / 512;                 // permute blocks
            k_count_v4<<<(e4 + 255) / 256, 256, 0, stream>>>(dst, cnt, slot, e4);
            k_scan_block<<<nb, 256, 0, stream>>>(cnt, off, bsum, dinv, n);
            k_scan_bsum<<<1, NBMAX, 0, stream>>>(bsum, bscan, nb);
            k_gemm_perm<<<gb + pb, 512, 0, stream>>>(x, W, dinv, h, n, gb,
                                                     src, dst, off, bscan, slot, ssrc, e4);
        } else {
            k_count_s<<<eb, 256, 0, stream>>>(dst, cnt, slot, e);
            k_scan_block<<<nb, 256, 0, stream>>>(cnt, off, bsum, dinv, n);
            k_scan_bsum<<<1, NBMAX, 0, stream>>>(bsum, bscan, nb);
            k_permute_s<<<eb, 256, 0, stream>>>(src, dst, off, bscan, slot, ssrc, e);
            k_gemm_perm<<<gb, 512, 0, stream>>>(x, W, dinv, h, n, gb,
                                                src, dst, off, bscan, slot, ssrc, 0);
        }
        int gblocks = ((size_t)n * 16 + 255) / 256;
        k_gather4<<<gblocks, 256, 0, stream>>>(h, dinv, off, cnt, bscan, ssrc, b, out, n);
    } else {
        // fp32 atomic-scatter fallback (needs only ~1.2 MB ws)
        float* dinv2 = (float*)(ws + nB);
        k_init<<<(n / 4 + 256) / 256, 256, 0, stream>>>(cnt, n);
        k_count_plain<<<eb, 256, 0, stream>>>(dst, cnt, e);
        k_dinv_only<<<nb, 256, 0, stream>>>(cnt, dinv2, n);
        k_self<<<(n * 32 + 255) / 256, 256, 0, stream>>>(x, dinv2, out, n);
        k_scatter_atomic<<<((size_t)e * 32 + 255) / 256, 256, 0, stream>>>(
            x, src, dst, dinv2, out, e);
        k_gemm_relu<<<(n + 127) / 128, 512, 0, stream>>>(out, W, b, n);
    }
}